// Round 6
// baseline (98.774 us; speedup 1.0000x reference)
//
#include <hip/hip_runtime.h>

// Problem constants (from reference): D=128, P=8, Q=40 (NUM_NEGATIVES=5*P)
#define DIMS   128
#define PNUM   8
#define QNUM   40
#define NBR    48   // P + Q

typedef float f32x4 __attribute__((ext_vector_type(4)));

// ---------------------------------------------------------------------------
// Kernel 0: convert x fp32 -> fp8 e4m3 (OCP) into workspace. Row = 128 B.
// ---------------------------------------------------------------------------
__global__ __launch_bounds__(256) void convert_f32_to_f8(
    const float* __restrict__ x, unsigned int* __restrict__ x8, int n8)
{
    const int stride = gridDim.x * blockDim.x;
    for (int i = blockIdx.x * blockDim.x + threadIdx.x; i < n8; i += stride) {
        const float4 v0 = reinterpret_cast<const float4*>(x)[2 * i];
        const float4 v1 = reinterpret_cast<const float4*>(x)[2 * i + 1];
        unsigned int a = __builtin_amdgcn_cvt_pk_fp8_f32(v0.x, v0.y, 0u, false);
        a = __builtin_amdgcn_cvt_pk_fp8_f32(v0.z, v0.w, a, true);
        unsigned int b = __builtin_amdgcn_cvt_pk_fp8_f32(v1.x, v1.y, 0u, false);
        b = __builtin_amdgcn_cvt_pk_fp8_f32(v1.z, v1.w, b, true);
        uint2 o; o.x = a; o.y = b;
        reinterpret_cast<uint2*>(x8)[i] = o;
    }
}

// ---------------------------------------------------------------------------
// Shared epilogue: per-lane sigmoid score s (lane<48) -> this node's loss v.
// ---------------------------------------------------------------------------
__device__ __forceinline__ float node_epilogue(float s, int lane, int N, int h)
{
    float pair_part = 0.0f;
    if (lane < NBR) {
        const float sp = log1pf(expf(s));            // softplus(s), s in (0,1)
        pair_part = (lane < PNUM) ? (sp - s) : sp;   // label 1 vs 0
    }
    // Group-of-8 sums: group 0 = pos mean, groups 1..5 = neg tuple means
    float gs = s;
    gs += __shfl_xor(gs, 1);
    gs += __shfl_xor(gs, 2);
    gs += __shfl_xor(gs, 4);

    float tuple_part = 0.0f;
    if ((lane & 7) == 0 && lane < NBR) {
        const float t  = gs * 0.125f;
        const float sp = log1pf(expf(t));
        tuple_part = (lane == 0) ? (sp - t) : sp;
    }
    const float pair_scale  = 1.0f / (48.0f * (float)N);
    const float tuple_scale = 1.0f / (6.0f  * (float)(N - h));
    return pair_part * pair_scale + tuple_part * tuple_scale;
}

// ---------------------------------------------------------------------------
// Kernel 1 (MFMA fp8 diag-GEMM): block = 16 consecutive nodes, 4 waves.
// A-tile = 16 node rows (fp8, loaded once); B-tile j = 16 gathered neighbor
// rows. mfma_f32_16x16x32_fp8_fp8 x4 (K=128) -> D = A.B^T; diagonal = the 16
// dot(x[n], x[idx[n][j]]). Wave w handles j = w, w+4, ..., w+44.
// D layout (HW-verified): col = lane&15, row = (lane>>4)*4 + reg.
// Diag element i sits in lane with lane&15==i, lane>>4==i>>2, reg = i&3.
// ---------------------------------------------------------------------------
__global__ __launch_bounds__(256) void node_loss_mfma(
    const unsigned char* __restrict__ x8,   // fp8 matrix, 128 B per row
    const int*           __restrict__ pos_idx,
    const int*           __restrict__ neg_idx,
    const int*           __restrict__ h_ptr,
    float*               __restrict__ ws,
    int N)
{
    __shared__ int   idx_sh[16][49];     // stride 49: conflict-free columns
    __shared__ float scores_sh[16][49];
    __shared__ float wsum[4];

    const int wv    = threadIdx.x >> 6;  // wave 0..3
    const int ln    = threadIdx.x & 63;
    const int row16 = ln & 15;           // A row / B col owned by this lane
    const int kq    = ln >> 4;           // k-quarter (8 fp8 elems each)
    const size_t base = (size_t)blockIdx.x * 16;

    // Stage the 16x48 neighbor indices into LDS.
    for (int c = threadIdx.x; c < 16 * NBR; c += 256) {
        const int n = c / NBR, j = c % NBR;
        idx_sh[n][j] = (j < PNUM) ? pos_idx[(base + n) * PNUM + j]
                                  : neg_idx[(base + n) * QNUM + (j - PNUM)];
    }

    // A fragments: this lane's 8 fp8 of row (base+row16) at each k-step.
    const unsigned char* arow = x8 + (base + row16) * DIMS + kq * 8;
    const long long a0 = *reinterpret_cast<const long long*>(arow);
    const long long a1 = *reinterpret_cast<const long long*>(arow + 32);
    const long long a2 = *reinterpret_cast<const long long*>(arow + 64);
    const long long a3 = *reinterpret_cast<const long long*>(arow + 96);

    __syncthreads();

    const bool diag = (kq == (row16 >> 2));
    const int  r    = ln & 3;

#pragma unroll 2
    for (int t = 0; t < 12; ++t) {
        const int j  = wv + t * 4;
        const int nb = idx_sh[row16][j];
        const unsigned char* brow = x8 + (size_t)nb * DIMS + kq * 8;
        const long long b0 = *reinterpret_cast<const long long*>(brow);
        const long long b1 = *reinterpret_cast<const long long*>(brow + 32);
        const long long b2 = *reinterpret_cast<const long long*>(brow + 64);
        const long long b3 = *reinterpret_cast<const long long*>(brow + 96);

        f32x4 acc = {0.0f, 0.0f, 0.0f, 0.0f};
        acc = __builtin_amdgcn_mfma_f32_16x16x32_fp8_fp8(a0, b0, acc, 0, 0, 0);
        acc = __builtin_amdgcn_mfma_f32_16x16x32_fp8_fp8(a1, b1, acc, 0, 0, 0);
        acc = __builtin_amdgcn_mfma_f32_16x16x32_fp8_fp8(a2, b2, acc, 0, 0, 0);
        acc = __builtin_amdgcn_mfma_f32_16x16x32_fp8_fp8(a3, b3, acc, 0, 0, 0);

        if (diag) {
            const float d = (r == 0) ? acc[0] : (r == 1) ? acc[1]
                          : (r == 2) ? acc[2] : acc[3];
            scores_sh[row16][j] = d;   // score for node row16, neighbor j
        }
    }

    __syncthreads();

    // Epilogue: wave w handles nodes 4w..4w+3 with the 48-lane pattern.
    const int h = *h_ptr;
    float v = 0.0f;
#pragma unroll
    for (int q = 0; q < 4; ++q) {
        const int n = wv * 4 + q;
        float s = 0.0f;
        if (ln < NBR)
            s = 1.0f / (1.0f + expf(-scores_sh[n][ln]));
        v += node_epilogue(s, ln, N, h);
    }

    v += __shfl_xor(v, 1);
    v += __shfl_xor(v, 2);
    v += __shfl_xor(v, 4);
    v += __shfl_xor(v, 8);
    v += __shfl_xor(v, 16);
    v += __shfl_xor(v, 32);

    if (ln == 0) wsum[wv] = v;
    __syncthreads();
    if (threadIdx.x == 0)
        ws[blockIdx.x] = wsum[0] + wsum[1] + wsum[2] + wsum[3];
}

// ---------------------------------------------------------------------------
// fp32 fallback (proven) for N % 16 != 0 or tiny workspace.
// ---------------------------------------------------------------------------
__global__ __launch_bounds__(256) void node_loss_partial_f32(
    const float* __restrict__ x,
    const int*   __restrict__ pos_idx,
    const int*   __restrict__ neg_idx,
    const int*   __restrict__ h_ptr,
    float*       __restrict__ ws,
    int N)
{
    __shared__ float xn_sh[4][DIMS];
    __shared__ float wsum[4];

    const int wave = threadIdx.x >> 6;
    const int lane = threadIdx.x & 63;
    const int node = blockIdx.x * 4 + wave;

    if (node < N && lane < 32) {
        const float4* row = reinterpret_cast<const float4*>(x + (size_t)node * DIMS);
        reinterpret_cast<float4*>(xn_sh[wave])[lane] = row[lane];
    }
    __syncthreads();

    float v = 0.0f;
    if (node < N) {
        float s = 0.0f;
        if (lane < NBR) {
            const int nb = (lane < PNUM)
                ? pos_idx[node * PNUM + lane]
                : neg_idx[node * QNUM + (lane - PNUM)];
            const float4* nrow = reinterpret_cast<const float4*>(x + (size_t)nb * DIMS);
            const float4* xn4  = reinterpret_cast<const float4*>(xn_sh[wave]);
            float acc = 0.0f;
#pragma unroll
            for (int t = 0; t < DIMS / 4; ++t) {
                const float4 a = xn4[t];
                const float4 b = nrow[t];
                acc += a.x * b.x + a.y * b.y + a.z * b.z + a.w * b.w;
            }
            s = 1.0f / (1.0f + expf(-acc));
        }
        v = node_epilogue(s, lane, N, *h_ptr);
    }

    v += __shfl_xor(v, 1);
    v += __shfl_xor(v, 2);
    v += __shfl_xor(v, 4);
    v += __shfl_xor(v, 8);
    v += __shfl_xor(v, 16);
    v += __shfl_xor(v, 32);

    if (lane == 0) wsum[wave] = v;
    __syncthreads();
    if (threadIdx.x == 0)
        ws[blockIdx.x] = wsum[0] + wsum[1] + wsum[2] + wsum[3];
}

// ---------------------------------------------------------------------------
// Kernel 2: deterministic single-block reduction of per-block partials.
// ---------------------------------------------------------------------------
__global__ __launch_bounds__(256) void reduce_final(
    const float* __restrict__ ws, float* __restrict__ out, int nparts)
{
    __shared__ float sm[4];
    float acc = 0.0f;
    for (int i = threadIdx.x; i < nparts; i += 256) acc += ws[i];

    acc += __shfl_xor(acc, 1);
    acc += __shfl_xor(acc, 2);
    acc += __shfl_xor(acc, 4);
    acc += __shfl_xor(acc, 8);
    acc += __shfl_xor(acc, 16);
    acc += __shfl_xor(acc, 32);

    const int wave = threadIdx.x >> 6;
    const int lane = threadIdx.x & 63;
    if (lane == 0) sm[wave] = acc;
    __syncthreads();
    if (threadIdx.x == 0)
        out[0] = sm[0] + sm[1] + sm[2] + sm[3];
}

extern "C" void kernel_launch(void* const* d_in, const int* in_sizes, int n_in,
                              void* d_out, int out_size, void* d_ws, size_t ws_size,
                              hipStream_t stream) {
    const float* x   = (const float*)d_in[0];
    const int*   pos = (const int*)d_in[1];
    const int*   neg = (const int*)d_in[2];
    const int*   h   = (const int*)d_in[3];

    const int N = in_sizes[0] / DIMS;  // 50000

    const size_t x8_bytes = (size_t)N * DIMS;  // 6.4 MB (1 B/elem)
    const int    ntiles   = N / 16;            // 3125 when N % 16 == 0
    const size_t need     = x8_bytes + (size_t)(ntiles + 1) * sizeof(float);

    if ((N % 16 == 0) && ws_size >= need) {
        unsigned char* x8 = (unsigned char*)d_ws;
        float* partials   = (float*)((char*)d_ws + x8_bytes);  // 128B-aligned
        const int n8 = N * DIMS / 8;
        convert_f32_to_f8<<<2048, 256, 0, stream>>>(x, (unsigned int*)x8, n8);
        node_loss_mfma<<<ntiles, 256, 0, stream>>>(x8, pos, neg, h, partials, N);
        reduce_final<<<1, 256, 0, stream>>>(partials, (float*)d_out, ntiles);
    } else {
        float* partials = (float*)d_ws;
        const int nblocks = (N + 3) / 4;
        node_loss_partial_f32<<<nblocks, 256, 0, stream>>>(x, pos, neg, h, partials, N);
        reduce_final<<<1, 256, 0, stream>>>(partials, (float*)d_out, nblocks);
    }
}

// Round 7
// 65.645 us; speedup vs baseline: 1.5047x; 1.5047x over previous
//
#include <hip/hip_runtime.h>

// Problem constants (from reference): D=128, P=8, Q=40 (NUM_NEGATIVES=5*P)
#define DIMS   128
#define PNUM   8
#define QNUM   40
#define NBR    48   // P + Q

typedef float f32x4 __attribute__((ext_vector_type(4)));

// ---------------------------------------------------------------------------
// Kernel 0: convert x fp32 -> fp8 e4m3 in MFMA-friendly permuted row layout.
// Row byte pos = kq*32 + kblock*8 + e  (orig k = kblock*32 + kq*8 + e), so a
// lane's 4 MFMA A/B fragments (one per kblock at fixed kq) are 32 contiguous
// bytes. Same permutation on both operands => diag(A.B^T) unchanged.
// One thread = 8 output bytes: unit u -> row=u>>4, sub=u&15 (sub=kq*4+kblock).
// ---------------------------------------------------------------------------
__global__ __launch_bounds__(256) void convert_f32_to_f8_perm(
    const float* __restrict__ x, unsigned int* __restrict__ x8, int nunits)
{
    const int stride = gridDim.x * blockDim.x;
    for (int u = blockIdx.x * blockDim.x + threadIdx.x; u < nunits; u += stride) {
        const int row = u >> 4;
        const int sub = u & 15;          // kq = sub>>2, kb = sub&3
        const int kq  = sub >> 2;
        const int kb  = sub & 3;
        const float4* src =
            reinterpret_cast<const float4*>(x + (size_t)row * DIMS + kb * 32 + kq * 8);
        const float4 v0 = src[0];
        const float4 v1 = src[1];
        unsigned int a = __builtin_amdgcn_cvt_pk_fp8_f32(v0.x, v0.y, 0u, false);
        a = __builtin_amdgcn_cvt_pk_fp8_f32(v0.z, v0.w, a, true);
        unsigned int b = __builtin_amdgcn_cvt_pk_fp8_f32(v1.x, v1.y, 0u, false);
        b = __builtin_amdgcn_cvt_pk_fp8_f32(v1.z, v1.w, b, true);
        uint2 o; o.x = a; o.y = b;
        // out byte offset = row*128 + sub*8  (= row*128 + kq*32 + kb*8)
        reinterpret_cast<uint2*>(x8)[u] = o;
    }
}

// ---------------------------------------------------------------------------
// Shared epilogue: per-lane sigmoid score s (lane<48) -> this node's loss v.
// ---------------------------------------------------------------------------
__device__ __forceinline__ float node_epilogue(float s, int lane, int N, int h)
{
    float pair_part = 0.0f;
    if (lane < NBR) {
        const float sp = log1pf(expf(s));            // softplus(s), s in (0,1)
        pair_part = (lane < PNUM) ? (sp - s) : sp;   // label 1 vs 0
    }
    // Group-of-8 sums: group 0 = pos mean, groups 1..5 = neg tuple means
    float gs = s;
    gs += __shfl_xor(gs, 1);
    gs += __shfl_xor(gs, 2);
    gs += __shfl_xor(gs, 4);

    float tuple_part = 0.0f;
    if ((lane & 7) == 0 && lane < NBR) {
        const float t  = gs * 0.125f;
        const float sp = log1pf(expf(t));
        tuple_part = (lane == 0) ? (sp - t) : sp;
    }
    const float pair_scale  = 1.0f / (48.0f * (float)N);
    const float tuple_scale = 1.0f / (6.0f  * (float)(N - h));
    return pair_part * pair_scale + tuple_part * tuple_scale;
}

// ---------------------------------------------------------------------------
// Kernel 1 (MFMA fp8 diag-GEMM, software-pipelined): block = 16 nodes, 4
// waves; wave wv handles j = wv + 4t, t=0..11, in 3 groups of 4 tiles with
// double-buffered register staging (load group g+1 before computing group g).
// Per tile: 2x16B contiguous loads (permuted layout) + 4 MFMAs in two
// independent chains. Diagonal of D = the 16 wanted dots.
// D layout (HW-verified): col = lane&15, row = (lane>>4)*4 + reg.
// ---------------------------------------------------------------------------
__global__ __launch_bounds__(256) void node_loss_mfma(
    const unsigned char* __restrict__ x8,   // fp8 matrix, permuted 128 B rows
    const int*           __restrict__ pos_idx,
    const int*           __restrict__ neg_idx,
    const int*           __restrict__ h_ptr,
    float*               __restrict__ ws,
    int N)
{
    __shared__ int   idx_sh[16][49];     // stride 49: conflict-free columns
    __shared__ float scores_sh[16][49];
    __shared__ float wsum[4];

    const int wv    = threadIdx.x >> 6;  // wave 0..3
    const int ln    = threadIdx.x & 63;
    const int row16 = ln & 15;           // A row / B col owned by this lane
    const int kq    = ln >> 4;           // k-quarter
    const size_t base = (size_t)blockIdx.x * 16;

    // A fragments: 32 contiguous bytes (permuted layout) of row base+row16.
    const ulonglong2* ap = reinterpret_cast<const ulonglong2*>(
        x8 + (base + row16) * DIMS + kq * 32);
    const ulonglong2 a01 = ap[0];   // .x = kblock0, .y = kblock1
    const ulonglong2 a23 = ap[1];   // .x = kblock2, .y = kblock3

    // Stage the 16x48 neighbor indices into LDS.
    for (int c = threadIdx.x; c < 16 * NBR; c += 256) {
        const int n = c / NBR, j = c % NBR;
        idx_sh[n][j] = (j < PNUM) ? pos_idx[(base + n) * PNUM + j]
                                  : neg_idx[(base + n) * QNUM + (j - PNUM)];
    }
    __syncthreads();

    const bool diag = (kq == (row16 >> 2));
    const int  r    = ln & 3;

    ulonglong2 bA[4][2], bB[4][2];

#define LOADG(BUF, G)                                                         \
    {                                                                         \
        _Pragma("unroll")                                                     \
        for (int u = 0; u < 4; ++u) {                                         \
            const int nb = idx_sh[row16][wv + ((G) * 4 + u) * 4];             \
            const ulonglong2* bp = reinterpret_cast<const ulonglong2*>(       \
                x8 + (size_t)nb * DIMS + kq * 32);                            \
            BUF[u][0] = bp[0];                                                \
            BUF[u][1] = bp[1];                                                \
        }                                                                     \
    }

#define COMPUTEG(BUF, G)                                                      \
    {                                                                         \
        _Pragma("unroll")                                                     \
        for (int u = 0; u < 4; ++u) {                                         \
            f32x4 acc01 = {0.f, 0.f, 0.f, 0.f};                               \
            f32x4 acc23 = {0.f, 0.f, 0.f, 0.f};                               \
            acc01 = __builtin_amdgcn_mfma_f32_16x16x32_fp8_fp8(               \
                (long long)a01.x, (long long)BUF[u][0].x, acc01, 0, 0, 0);    \
            acc01 = __builtin_amdgcn_mfma_f32_16x16x32_fp8_fp8(               \
                (long long)a01.y, (long long)BUF[u][0].y, acc01, 0, 0, 0);    \
            acc23 = __builtin_amdgcn_mfma_f32_16x16x32_fp8_fp8(               \
                (long long)a23.x, (long long)BUF[u][1].x, acc23, 0, 0, 0);    \
            acc23 = __builtin_amdgcn_mfma_f32_16x16x32_fp8_fp8(               \
                (long long)a23.y, (long long)BUF[u][1].y, acc23, 0, 0, 0);    \
            if (diag) {                                                       \
                const float d01 = (r == 0) ? acc01[0] : (r == 1) ? acc01[1]   \
                               : (r == 2) ? acc01[2] : acc01[3];              \
                const float d23 = (r == 0) ? acc23[0] : (r == 1) ? acc23[1]   \
                               : (r == 2) ? acc23[2] : acc23[3];              \
                scores_sh[row16][wv + ((G) * 4 + u) * 4] = d01 + d23;         \
            }                                                                 \
        }                                                                     \
    }

    LOADG(bA, 0);
    LOADG(bB, 1);
    COMPUTEG(bA, 0);
    LOADG(bA, 2);
    COMPUTEG(bB, 1);
    COMPUTEG(bA, 2);

#undef LOADG
#undef COMPUTEG

    __syncthreads();

    // Epilogue: wave w handles nodes 4w..4w+3 with the 48-lane pattern.
    const int h = *h_ptr;
    float v = 0.0f;
#pragma unroll
    for (int q = 0; q < 4; ++q) {
        const int n = wv * 4 + q;
        float s = 0.0f;
        if (ln < NBR)
            s = 1.0f / (1.0f + expf(-scores_sh[n][ln]));
        v += node_epilogue(s, ln, N, h);
    }

    v += __shfl_xor(v, 1);
    v += __shfl_xor(v, 2);
    v += __shfl_xor(v, 4);
    v += __shfl_xor(v, 8);
    v += __shfl_xor(v, 16);
    v += __shfl_xor(v, 32);

    if (ln == 0) wsum[wv] = v;
    __syncthreads();
    if (threadIdx.x == 0)
        ws[blockIdx.x] = wsum[0] + wsum[1] + wsum[2] + wsum[3];
}

// ---------------------------------------------------------------------------
// fp32 fallback (proven) for N % 16 != 0 or tiny workspace.
// ---------------------------------------------------------------------------
__global__ __launch_bounds__(256) void node_loss_partial_f32(
    const float* __restrict__ x,
    const int*   __restrict__ pos_idx,
    const int*   __restrict__ neg_idx,
    const int*   __restrict__ h_ptr,
    float*       __restrict__ ws,
    int N)
{
    __shared__ float xn_sh[4][DIMS];
    __shared__ float wsum[4];

    const int wave = threadIdx.x >> 6;
    const int lane = threadIdx.x & 63;
    const int node = blockIdx.x * 4 + wave;

    if (node < N && lane < 32) {
        const float4* row = reinterpret_cast<const float4*>(x + (size_t)node * DIMS);
        reinterpret_cast<float4*>(xn_sh[wave])[lane] = row[lane];
    }
    __syncthreads();

    float v = 0.0f;
    if (node < N) {
        float s = 0.0f;
        if (lane < NBR) {
            const int nb = (lane < PNUM)
                ? pos_idx[node * PNUM + lane]
                : neg_idx[node * QNUM + (lane - PNUM)];
            const float4* nrow = reinterpret_cast<const float4*>(x + (size_t)nb * DIMS);
            const float4* xn4  = reinterpret_cast<const float4*>(xn_sh[wave]);
            float acc = 0.0f;
#pragma unroll
            for (int t = 0; t < DIMS / 4; ++t) {
                const float4 a = xn4[t];
                const float4 b = nrow[t];
                acc += a.x * b.x + a.y * b.y + a.z * b.z + a.w * b.w;
            }
            s = 1.0f / (1.0f + expf(-acc));
        }
        v = node_epilogue(s, lane, N, *h_ptr);
    }

    v += __shfl_xor(v, 1);
    v += __shfl_xor(v, 2);
    v += __shfl_xor(v, 4);
    v += __shfl_xor(v, 8);
    v += __shfl_xor(v, 16);
    v += __shfl_xor(v, 32);

    if (lane == 0) wsum[wave] = v;
    __syncthreads();
    if (threadIdx.x == 0)
        ws[blockIdx.x] = wsum[0] + wsum[1] + wsum[2] + wsum[3];
}

// ---------------------------------------------------------------------------
// Kernel 2: deterministic single-block reduction of per-block partials.
// ---------------------------------------------------------------------------
__global__ __launch_bounds__(256) void reduce_final(
    const float* __restrict__ ws, float* __restrict__ out, int nparts)
{
    __shared__ float sm[4];
    float acc = 0.0f;
    for (int i = threadIdx.x; i < nparts; i += 256) acc += ws[i];

    acc += __shfl_xor(acc, 1);
    acc += __shfl_xor(acc, 2);
    acc += __shfl_xor(acc, 4);
    acc += __shfl_xor(acc, 8);
    acc += __shfl_xor(acc, 16);
    acc += __shfl_xor(acc, 32);

    const int wave = threadIdx.x >> 6;
    const int lane = threadIdx.x & 63;
    if (lane == 0) sm[wave] = acc;
    __syncthreads();
    if (threadIdx.x == 0)
        out[0] = sm[0] + sm[1] + sm[2] + sm[3];
}

extern "C" void kernel_launch(void* const* d_in, const int* in_sizes, int n_in,
                              void* d_out, int out_size, void* d_ws, size_t ws_size,
                              hipStream_t stream) {
    const float* x   = (const float*)d_in[0];
    const int*   pos = (const int*)d_in[1];
    const int*   neg = (const int*)d_in[2];
    const int*   h   = (const int*)d_in[3];

    const int N = in_sizes[0] / DIMS;  // 50000

    const size_t x8_bytes = (size_t)N * DIMS;  // 6.4 MB (1 B/elem)
    const int    ntiles   = N / 16;            // 3125 when N % 16 == 0
    const size_t need     = x8_bytes + (size_t)(ntiles + 1) * sizeof(float);

    if ((N % 16 == 0) && ws_size >= need) {
        unsigned char* x8 = (unsigned char*)d_ws;
        float* partials   = (float*)((char*)d_ws + x8_bytes);  // 128B-aligned
        const int nunits = N * 16;  // 8 output bytes per unit
        convert_f32_to_f8_perm<<<2048, 256, 0, stream>>>(x, (unsigned int*)x8, nunits);
        node_loss_mfma<<<ntiles, 256, 0, stream>>>(x8, pos, neg, h, partials, N);
        reduce_final<<<1, 256, 0, stream>>>(partials, (float*)d_out, ntiles);
    } else {
        float* partials = (float*)d_ws;
        const int nblocks = (N + 3) / 4;
        node_loss_partial_f32<<<nblocks, 256, 0, stream>>>(x, pos, neg, h, partials, N);
        reduce_final<<<1, 256, 0, stream>>>(partials, (float*)d_out, nblocks);
    }
}